// Round 7
// baseline (736.994 us; speedup 1.0000x reference)
//
#include <hip/hip_runtime.h>
#include <math.h>

#define NHEADS   64
#define EMB      2048
#define STATE    128
#define KCONV    4
#define HEAD_DIM 64
#define CHUNK    128
#define SEQL     2048
#define NBATCH   2
#define NCH      (SEQL/CHUNK)          // 16
#define INTER    (NHEADS*HEAD_DIM)     // 4096
#define CONVD    (INTER + 2*STATE)     // 4352
#define PROJD    (INTER + CONVD + NHEADS) // 8512
#define ROWS     (NBATCH*SEQL)         // 4096
#define EPSV     1e-6f

__device__ __forceinline__ float sigmoidf_(float x){ return 1.f/(1.f+__expf(-x)); }

// ---- bf16 (stored as ushort) helpers, f32 math everywhere -----------------
__device__ __forceinline__ float b2f(ushort u){
  union{float f; unsigned u;} x; x.u = ((unsigned)u)<<16; return x.f;
}
__device__ __forceinline__ ushort f2b(float f){
  union{float f; unsigned u;} x; x.f=f;
  unsigned r = x.u + 0x7FFFu + ((x.u>>16)&1u);
  return (ushort)(r>>16);
}
__device__ __forceinline__ float4 ld4(const float* p){ return *(const float4*)p; }
__device__ __forceinline__ float4 ld4(const ushort* p){
  ushort4 v = *(const ushort4*)p;
  return make_float4(b2f(v.x),b2f(v.y),b2f(v.z),b2f(v.w));
}
__device__ __forceinline__ void st4(float* p, float4 v){ *(float4*)p = v; }
__device__ __forceinline__ void st4(ushort* p, float4 v){
  ushort4 o; o.x=f2b(v.x); o.y=f2b(v.y); o.z=f2b(v.z); o.w=f2b(v.w);
  *(ushort4*)p = o;
}
__device__ __forceinline__ void stc(float* p, float v){ *p = v; }
__device__ __forceinline__ void stc(ushort* p, float v){ *p = f2b(v); }

// ---------------------------------------------------------------------------
// f32 -> bf16 bulk convert (n multiple of 8)
// ---------------------------------------------------------------------------
__global__ __launch_bounds__(256) void f32_to_bf16_kernel(
    const float* __restrict__ in, ushort* __restrict__ out, long n)
{
  long i = ((long)blockIdx.x*256 + threadIdx.x) * 8;
  if (i >= n) return;
  float4 a = *(const float4*)(in + i);
  float4 b = *(const float4*)(in + i + 4);
  st4(out + i, a);
  st4(out + i + 4, b);
}

typedef __attribute__((ext_vector_type(8))) short short8v;   // 8 bf16 = 4 VGPR
typedef __attribute__((ext_vector_type(4))) float float4v;

#define GLL16(g, l) __builtin_amdgcn_global_load_lds( \
    (const __attribute__((address_space(1))) void*)(g), \
    (__attribute__((address_space(3))) void*)(l), 16, 0, 0)

#define SBAR asm volatile("s_barrier" ::: "memory")

// ---------------------------------------------------------------------------
// Deep-pipelined MFMA bf16 NT GEMM: C[m,n] = sum_k A[m,k]*B[n,k]
// Tile 128(M) x 256(N), BK=32. 512 threads = 8 waves (2M x 4N), per-wave
// 64x64 (4x4 frags of 16x16x32). 4 LDS buffers, 3-tile prefetch lookahead,
// counted vmcnt (9 steady - never drained), raw s_barrier, setprio around
// MFMA clusters. LDS XOR-swizzle col8^=((row>>1)&3) applied to global SOURCE
// (gload_lds dest linear) and to reads -> bank-conflict-free b128.
// M % 128 == 0; N guarded (B-row clamp + store mask). K % 32 == 0, K/32 >= 4.
// ---------------------------------------------------------------------------
template<typename TC>
__global__ __launch_bounds__(512, 2) void gemm_pipe_bt(
    const ushort* __restrict__ A, int lda,
    const ushort* __restrict__ B, int ldb,
    TC* __restrict__ C, int ldc,
    int N, int K)
{
  __shared__ ushort ASb[4][128*32];   // 4 x 8 KB
  __shared__ ushort BSb[4][256*32];   // 4 x 16 KB
  const int t = threadIdx.x;
  const int lt = t & 63, w = t >> 6;
  const int wr = w >> 2, wc = w & 3;           // 2M x 4N waves

  // XCD-aware bijective swizzle (nwg % 8 == 0 at both call sites)
  const int nwg = gridDim.x * gridDim.y;
  int orig = blockIdx.x + gridDim.x * blockIdx.y;
  int tile = (orig & 7) * (nwg >> 3) + (orig >> 3);
  const int m0 = (tile / gridDim.x) * 128;
  const int n0 = (tile % gridDim.x) * 256;

  // staging addresses: thread t covers lds row r = t>>2 (and r+128 for B),
  // col-slot t&3; source col pre-swizzled so linear LDS + swizzled read match.
  const int rs = t >> 2;                        // 0..127
  const int cs = ((t & 3) ^ ((rs >> 1) & 3)) * 8;  // (note: (128+rs)>>1 &3 == same)
  const long asrc  = (long)(m0 + rs) * lda + cs;
  const long bsrc0 = (long)min(n0 + rs, N-1) * ldb + cs;
  const long bsrc1 = (long)min(n0 + 128 + rs, N-1) * ldb + cs;
  const int ldst = t * 16;                      // linear byte dest in buffer

  auto STAGE = [&](int kt) {
    int b = kt & 3;
    long ko = (long)kt * 32;
    GLL16(A + asrc  + ko, (char*)ASb[b] + ldst);
    GLL16(B + bsrc0 + ko, (char*)BSb[b] + ldst);
    GLL16(B + bsrc1 + ko, (char*)BSb[b] + 8192 + ldst);
  };

  float4v acc[4][4];
  #pragma unroll
  for (int i=0;i<4;++i)
    #pragma unroll
    for (int j=0;j<4;++j) acc[i][j] = float4v{0.f,0.f,0.f,0.f};

  const int NT = K >> 5;
  STAGE(0); STAGE(1); STAGE(2);

  const int lr = lt & 15, lks = lt >> 4;        // frag row-in-16, col8 slot
  for (int kt = 0; kt < NT; ++kt) {
    if (kt + 3 < NT) STAGE(kt + 3);
    if (kt < NT-3)       asm volatile("s_waitcnt vmcnt(9)" ::: "memory");
    else if (kt == NT-3) asm volatile("s_waitcnt vmcnt(6)" ::: "memory");
    else if (kt == NT-2) asm volatile("s_waitcnt vmcnt(3)" ::: "memory");
    else                 asm volatile("s_waitcnt vmcnt(0)" ::: "memory");
    SBAR;                                        // tile kt complete, all waves
    const char* ab = (const char*)ASb[kt & 3];
    const char* bb = (const char*)BSb[kt & 3];
    short8v afr[4], bfr[4];
    #pragma unroll
    for (int mi = 0; mi < 4; ++mi) {
      int rr = wr*64 + mi*16 + lr;
      afr[mi] = *(const short8v*)(ab + rr*64 + ((lks ^ ((rr>>1)&3))*16));
    }
    #pragma unroll
    for (int nj = 0; nj < 2; ++nj) {
      int rr = wc*64 + nj*16 + lr;
      bfr[nj] = *(const short8v*)(bb + rr*64 + ((lks ^ ((rr>>1)&3))*16));
    }
    __builtin_amdgcn_s_setprio(1);
    #pragma unroll
    for (int mi = 0; mi < 4; ++mi)
      #pragma unroll
      for (int nj = 0; nj < 2; ++nj)
        acc[mi][nj] = __builtin_amdgcn_mfma_f32_16x16x32_bf16(afr[mi], bfr[nj], acc[mi][nj], 0, 0, 0);
    __builtin_amdgcn_s_setprio(0);
    #pragma unroll
    for (int nj = 2; nj < 4; ++nj) {
      int rr = wc*64 + nj*16 + lr;
      bfr[nj] = *(const short8v*)(bb + rr*64 + ((lks ^ ((rr>>1)&3))*16));
    }
    __builtin_amdgcn_s_setprio(1);
    #pragma unroll
    for (int mi = 0; mi < 4; ++mi)
      #pragma unroll
      for (int nj = 2; nj < 4; ++nj)
        acc[mi][nj] = __builtin_amdgcn_mfma_f32_16x16x32_bf16(afr[mi], bfr[nj], acc[mi][nj], 0, 0, 0);
    __builtin_amdgcn_s_setprio(0);
    SBAR;                                        // all reads of buf kt&3 done
  }

  const int cr = (lt >> 4) * 4;   // C/D: col=lane&15, row=(lane>>4)*4+reg (m89)
  const int cc = lt & 15;
  #pragma unroll
  for (int mi = 0; mi < 4; ++mi) {
    #pragma unroll
    for (int nj = 0; nj < 4; ++nj) {
      int col = n0 + wc*64 + nj*16 + cc;
      if (col < N) {
        #pragma unroll
        for (int r = 0; r < 4; ++r) {
          int row = m0 + wr*64 + mi*16 + cr + r;
          stc(C + (long)row*ldc + col, acc[mi][nj][r]);
        }
      }
    }
  }
}

// ---------------------------------------------------------------------------
// SIMT NT GEMM (kept for the small per-chunk G = C B^T, 32 blocks of 128^3)
// ---------------------------------------------------------------------------
#define BM 128
#define BN 128
#define BKK 16

template<typename TA, typename TB, typename TC>
__global__ __launch_bounds__(256) void gemm_bnt(
    const TA* __restrict__ A, int lda, long sA,
    const TB* __restrict__ B, int ldb, long sB,
    TC* __restrict__ C, int ldc, long sC,
    int M, int N, int K)
{
  A += (long)blockIdx.z * sA;
  B += (long)blockIdx.z * sB;
  C += (long)blockIdx.z * sC;
  const int n0 = blockIdx.x * BN;
  const int m0 = blockIdx.y * BM;
  __shared__ float As[BKK][BM+4];
  __shared__ float Bs[BKK][BN+4];
  const int t = threadIdx.x;
  const int tx = t & 15, ty = t >> 4;
  float acc[8][8];
  #pragma unroll
  for (int i=0;i<8;++i)
    #pragma unroll
    for (int j=0;j<8;++j) acc[i][j]=0.f;

  for (int k0 = 0; k0 < K; k0 += BKK) {
    #pragma unroll
    for (int i = 0; i < 2; ++i) {
      int f = t + i*256;
      int row = f >> 2, kq = (f & 3) << 2;
      float4 v = ld4(A + (long)(m0+row)*lda + (k0 + kq));
      As[kq+0][row]=v.x; As[kq+1][row]=v.y; As[kq+2][row]=v.z; As[kq+3][row]=v.w;
      int gn = n0 + row;
      float4 w = make_float4(0.f,0.f,0.f,0.f);
      if (gn < N) w = ld4(B + (long)gn*ldb + (k0 + kq));
      Bs[kq+0][row]=w.x; Bs[kq+1][row]=w.y; Bs[kq+2][row]=w.z; Bs[kq+3][row]=w.w;
    }
    __syncthreads();
    #pragma unroll
    for (int k = 0; k < BKK; ++k) {
      float a[8], b[8];
      *(float4*)&a[0] = *(const float4*)&As[k][ty*8];
      *(float4*)&a[4] = *(const float4*)&As[k][ty*8+4];
      *(float4*)&b[0] = *(const float4*)&Bs[k][tx*8];
      *(float4*)&b[4] = *(const float4*)&Bs[k][tx*8+4];
      #pragma unroll
      for (int i = 0; i < 8; ++i)
        #pragma unroll
        for (int j = 0; j < 8; ++j)
          acc[i][j] = fmaf(a[i], b[j], acc[i][j]);
    }
    __syncthreads();
  }
  #pragma unroll
  for (int i = 0; i < 8; ++i) {
    int gm = m0 + ty*8 + i;
    #pragma unroll
    for (int j = 0; j < 8; j += 4) {
      int gn = n0 + tx*8 + j;
      if (gn < N)
        st4(C + (long)gm*ldc + gn,
            make_float4(acc[i][j],acc[i][j+1],acc[i][j+2],acc[i][j+3]));
    }
  }
}

// ---------------------------------------------------------------------------
// Depthwise causal conv (K=4) + bias + SiLU over proj cols [INTER, INTER+CONVD)
// ---------------------------------------------------------------------------
__global__ __launch_bounds__(256) void conv_silu_kernel(
    const ushort* __restrict__ proj, const float* __restrict__ cw,
    const float* __restrict__ cb, ushort* __restrict__ out)
{
  const int C4 = CONVD/4;
  long idx = (long)blockIdx.x*256 + threadIdx.x;
  if (idx >= (long)ROWS*C4) return;
  int r = (int)(idx / C4);
  int c = (int)(idx % C4) * 4;
  int tt = r & (SEQL-1);
  float4 bv = *(const float4*)(cb + c);
  float acc0=bv.x, acc1=bv.y, acc2=bv.z, acc3=bv.w;
  float4 w0 = *(const float4*)(cw + (c+0)*KCONV);
  float4 w1 = *(const float4*)(cw + (c+1)*KCONV);
  float4 w2 = *(const float4*)(cw + (c+2)*KCONV);
  float4 w3 = *(const float4*)(cw + (c+3)*KCONV);
  const float wj0[4] = {w0.x,w0.y,w0.z,w0.w};
  const float wj1[4] = {w1.x,w1.y,w1.z,w1.w};
  const float wj2[4] = {w2.x,w2.y,w2.z,w2.w};
  const float wj3[4] = {w3.x,w3.y,w3.z,w3.w};
  #pragma unroll
  for (int j = 0; j < KCONV; ++j) {
    int tr = tt - (KCONV-1) + j;
    if (tr >= 0) {
      float4 v = ld4(proj + (long)(r - (KCONV-1) + j)*PROJD + INTER + c);
      acc0 = fmaf(v.x, wj0[j], acc0);
      acc1 = fmaf(v.y, wj1[j], acc1);
      acc2 = fmaf(v.z, wj2[j], acc2);
      acc3 = fmaf(v.w, wj3[j], acc3);
    }
  }
  float4 o;
  o.x = acc0 * sigmoidf_(acc0);
  o.y = acc1 * sigmoidf_(acc1);
  o.z = acc2 * sigmoidf_(acc2);
  o.w = acc3 * sigmoidf_(acc3);
  st4(out + (long)r*CONVD + c, o);
}

// dt = softplus(dt_raw + bias)
__global__ void dt_kernel(const ushort* __restrict__ proj,
                          const float* __restrict__ dt_bias,
                          float* __restrict__ dtb)
{
  int idx = blockIdx.x*256 + threadIdx.x;
  if (idx >= ROWS*NHEADS) return;
  int r = idx >> 6, h = idx & 63;
  float xv = b2f(proj[(long)r*PROJD + INTER + CONVD + h]) + dt_bias[h];
  dtb[idx] = fmaxf(xv, 0.f) + __logf(1.f + __expf(-fabsf(xv)));
}

// per-(b,chunk,head) inclusive cumsum of A*dt over the chunk
__global__ void acum_kernel(const float* __restrict__ dtb,
                            const float* __restrict__ A_log,
                            float* __restrict__ acum)
{
  int idx = blockIdx.x*256 + threadIdx.x;
  if (idx >= NBATCH*NCH*NHEADS) return;
  int h = idx & 63, bc = idx >> 6;
  float Ah = -__expf(A_log[h]);
  const float* d = dtb + (long)bc*CHUNK*NHEADS + h;
  float* o = acum + (long)idx*CHUNK;
  float acc = 0.f;
  for (int l = 0; l < CHUNK; ++l) { acc = fmaf(Ah, d[l*NHEADS], acc); o[l] = acc; }
}

// ---------------------------------------------------------------------------
// MFMA states kernel: states[p,n] = sum_l (w[l]*hid[l,p]) * B[l,n]
// ---------------------------------------------------------------------------
__global__ __launch_bounds__(256) void states_mfma_kernel(
    const ushort* __restrict__ conv, const float* __restrict__ dtb,
    const float* __restrict__ acum, ushort* __restrict__ states)
{
  const int h = blockIdx.x, c = blockIdx.y, b = blockIdx.z;
  const int bc = b*NCH + c;
  const long r0 = (long)bc*CHUNK;
  __shared__ ushort Ahi[64][136];   // (w*hid)^T hi: [p][l]
  __shared__ ushort Alo[64][136];   // lo residual
  __shared__ ushort Bt[128][136];   // B^T: [n][l]
  __shared__ float arow[CHUNK];
  __shared__ float wrow[CHUNK];
  const int t = threadIdx.x;
  const int lt = t & 63, w = t >> 6;
  const int lr = lt & 15, lk = (lt >> 4) * 8;

  if (t < CHUNK) arow[t] = acum[((long)bc*NHEADS + h)*CHUNK + t];
  __syncthreads();
  if (t < CHUNK) wrow[t] = dtb[(r0 + t)*NHEADS + h] * __expf(arow[CHUNK-1] - arow[t]);
  __syncthreads();

  for (int i = t; i < CHUNK*HEAD_DIM/8; i += 256) {
    int l = i >> 3, p0 = (i & 7) * 8;
    short8v v = *(const short8v*)(conv + (r0+l)*CONVD + h*HEAD_DIM + p0);
    float wl = wrow[l];
    #pragma unroll
    for (int j = 0; j < 8; ++j) {
      float f = b2f((ushort)v[j]) * wl;
      ushort hb = f2b(f);
      Ahi[p0+j][l] = hb;
      Alo[p0+j][l] = f2b(f - b2f(hb));
    }
  }
  for (int i = t; i < CHUNK*STATE/8; i += 256) {
    int l = i >> 4, n0 = (i & 15) * 8;
    short8v v = *(const short8v*)(conv + (r0+l)*CONVD + INTER + n0);
    #pragma unroll
    for (int j = 0; j < 8; ++j) Bt[n0+j][l] = (ushort)v[j];
  }
  __syncthreads();

  float4v acc[8];
  #pragma unroll
  for (int j = 0; j < 8; ++j) acc[j] = float4v{0,0,0,0};
  #pragma unroll
  for (int kk = 0; kk < 4; ++kk) {
    short8v ahi = *(const short8v*)&Ahi[w*16 + lr][kk*32 + lk];
    short8v alo = *(const short8v*)&Alo[w*16 + lr][kk*32 + lk];
    #pragma unroll
    for (int nj = 0; nj < 8; ++nj) {
      short8v bv = *(const short8v*)&Bt[nj*16 + lr][kk*32 + lk];
      acc[nj] = __builtin_amdgcn_mfma_f32_16x16x32_bf16(ahi, bv, acc[nj], 0, 0, 0);
      acc[nj] = __builtin_amdgcn_mfma_f32_16x16x32_bf16(alo, bv, acc[nj], 0, 0, 0);
    }
  }
  ushort* so = states + ((long)bc*NHEADS + h)*HEAD_DIM*STATE;
  const int cr = (lt >> 4) * 4, cc = lt & 15;
  #pragma unroll
  for (int nj = 0; nj < 8; ++nj)
    #pragma unroll
    for (int r = 0; r < 4; ++r)
      so[(w*16 + cr + r)*STATE + nj*16 + cc] = f2b(acc[nj][r]);
}

// in-place inter-chunk scan: states[c] <- init_state entering chunk c
__global__ __launch_bounds__(256) void scan_kernel(
    ushort* __restrict__ states, const float* __restrict__ acum)
{
  const int bh = blockIdx.x;          // b*NHEADS + h
  const int b = bh >> 6, h = bh & 63;
  const int t = threadIdx.x;
  float acc[32];
  #pragma unroll
  for (int i=0;i<32;++i) acc[i]=0.f;
  for (int c = 0; c < NCH; ++c) {
    const long bch = ((long)(b*NCH + c)*NHEADS + h);
    float lam = __expf(acum[bch*CHUNK + CHUNK-1]);
    ushort* sb = states + bch*HEAD_DIM*STATE;
    #pragma unroll
    for (int i = 0; i < 32; ++i) {
      float v = b2f(sb[t + i*256]);
      sb[t + i*256] = f2b(acc[i]);
      acc[i] = fmaf(acc[i], lam, v);
    }
  }
}

// ---------------------------------------------------------------------------
// MFMA y-kernel (verified R5/R6)
// ---------------------------------------------------------------------------
__global__ __launch_bounds__(256) void y_mfma_kernel(
    const ushort* __restrict__ conv, const float* __restrict__ dtb,
    const float* __restrict__ acum, const float* __restrict__ G,
    const ushort* __restrict__ states, const float* __restrict__ Dp,
    ushort* __restrict__ proj)
{
  const int h = blockIdx.x;
  const int c = blockIdx.y >> 1, mh = blockIdx.y & 1;
  const int b = blockIdx.z;
  const int bc = b*NCH + c;
  const int mbase = mh * 64;
  const long r0 = (long)bc*CHUNK;

  __shared__ float  Af[64][132];     // W (f32), then C (f32 from bf16, exact)
  __shared__ ushort B0[64][136];     // hid^T: B0[p][s], s over FULL chunk
  __shared__ ushort B1[64][136];     // init:  B1[p][n]
  __shared__ float arow[CHUNK];
  __shared__ float dtr[CHUNK];
  __shared__ float el[64];

  const int t = threadIdx.x;
  const int lt = t & 63, w = t >> 6;
  const int lr = lt & 15, lk = (lt >> 4) * 8;

  if (t < CHUNK) {
    arow[t] = acum[((long)bc*NHEADS + h)*CHUNK + t];
    dtr[t]  = dtb[(r0 + t)*NHEADS + h];
  }
  __syncthreads();

  if (t < 64) el[t] = __expf(arow[mbase + t]);
  for (int i = t; i < CHUNK*HEAD_DIM/8; i += 256) {
    int s = i >> 3, p0 = (i & 7) * 8;
    short8v v = *(const short8v*)(conv + (r0+s)*CONVD + h*HEAD_DIM + p0);
    #pragma unroll
    for (int j = 0; j < 8; ++j) B0[p0+j][s] = (ushort)v[j];
  }
  {
    const ushort* stb = states + ((long)bc*NHEADS + h)*HEAD_DIM*STATE;
    for (int i = t; i < HEAD_DIM*STATE/8; i += 256) {
      int p = i >> 4, n0 = (i & 15) * 8;
      *(short8v*)&B1[p][n0] = *(const short8v*)(stb + p*STATE + n0);
    }
  }
  {
    const float* Gb = G + (long)bc*CHUNK*CHUNK;
    for (int i = t; i < 64*CHUNK; i += 256) {
      int ll = i >> 7, s = i & 127;
      int l = mbase + ll;
      float wv = 0.f;
      if (s <= l) wv = Gb[l*CHUNK + s] * __expf(arow[l] - arow[s]) * dtr[s];
      Af[ll][s] = wv;
    }
  }
  __syncthreads();

  float4v acc1[4], acc2[4];
  #pragma unroll
  for (int j = 0; j < 4; ++j) { acc1[j] = float4v{0,0,0,0}; acc2[j] = float4v{0,0,0,0}; }

  // mm1: Y_diag, W split hi/lo
  #pragma unroll
  for (int kk = 0; kk < 4; ++kk) {
    const float* ap = &Af[w*16 + lr][kk*32 + lk];
    float a8[8];
    *(float4*)&a8[0] = *(const float4*)ap;
    *(float4*)&a8[4] = *(const float4*)(ap + 4);
    short8v ahi, alo;
    #pragma unroll
    for (int e = 0; e < 8; ++e) {
      ushort hb = f2b(a8[e]);
      float rem = a8[e] - b2f(hb);
      ahi[e] = (short)hb;
      alo[e] = (short)f2b(rem);
    }
    #pragma unroll
    for (int nj = 0; nj < 4; ++nj) {
      short8v bfv = *(const short8v*)&B0[nj*16 + lr][kk*32 + lk];
      acc1[nj] = __builtin_amdgcn_mfma_f32_16x16x32_bf16(ahi, bfv, acc1[nj], 0, 0, 0);
      acc1[nj] = __builtin_amdgcn_mfma_f32_16x16x32_bf16(alo, bfv, acc1[nj], 0, 0, 0);
    }
  }
  __syncthreads();

  for (int i = t; i < 64*STATE; i += 256) {
    int ll = i >> 7, n = i & 127;
    Af[ll][n] = b2f(conv[(r0 + mbase + ll)*CONVD + INTER + STATE + n]);
  }
  __syncthreads();

  // mm2: C @ init^T (exact)
  #pragma unroll
  for (int kk = 0; kk < 4; ++kk) {
    const float* ap = &Af[w*16 + lr][kk*32 + lk];
    float a8[8];
    *(float4*)&a8[0] = *(const float4*)ap;
    *(float4*)&a8[4] = *(const float4*)(ap + 4);
    short8v ahi;
    #pragma unroll
    for (int e = 0; e < 8; ++e) ahi[e] = (short)f2b(a8[e]);
    #pragma unroll
    for (int nj = 0; nj < 4; ++nj) {
      short8v bfv = *(const short8v*)&B1[nj*16 + lr][kk*32 + lk];
      acc2[nj] = __builtin_amdgcn_mfma_f32_16x16x32_bf16(ahi, bfv, acc2[nj], 0, 0, 0);
    }
  }

  const float Dh = Dp[h];
  const int cr = (lt >> 4) * 4, cc = lt & 15;
  #pragma unroll
  for (int nj = 0; nj < 4; ++nj) {
    int p = nj*16 + cc;
    #pragma unroll
    for (int r = 0; r < 4; ++r) {
      int ll = w*16 + cr + r;
      float hid_raw = b2f(B0[p][mbase + ll]);
      float yv = acc1[nj][r] + el[ll]*acc2[nj][r] + Dh*hid_raw;
      proj[(r0 + mbase + ll)*PROJD + INTER + h*HEAD_DIM + p] = f2b(yv);
    }
  }
}

// yg = y*silu(gate); rmsnorm; write yn back in place (per row)
__global__ __launch_bounds__(256) void gate_norm_kernel(
    ushort* __restrict__ proj, const float* __restrict__ nw)
{
  const int r = blockIdx.x;
  const int t = threadIdx.x;
  __shared__ float red[256];
  ushort* gate = proj + (long)r*PROJD;
  ushort* y = gate + INTER;
  float vals[16];
  float ss = 0.f;
  #pragma unroll
  for (int k = 0; k < 4; ++k) {
    int j = (t + k*256) * 4;
    float4 g = ld4(gate + j);
    float4 yv = ld4(y + j);
    float v0 = yv.x * g.x * sigmoidf_(g.x);
    float v1 = yv.y * g.y * sigmoidf_(g.y);
    float v2 = yv.z * g.z * sigmoidf_(g.z);
    float v3 = yv.w * g.w * sigmoidf_(g.w);
    vals[k*4+0]=v0; vals[k*4+1]=v1; vals[k*4+2]=v2; vals[k*4+3]=v3;
    ss += v0*v0 + v1*v1 + v2*v2 + v3*v3;
  }
  red[t] = ss;
  __syncthreads();
  for (int sft = 128; sft > 0; sft >>= 1) {
    if (t < sft) red[t] += red[t+sft];
    __syncthreads();
  }
  float scale = rsqrtf(red[0] / (float)INTER + EPSV);
  #pragma unroll
  for (int k = 0; k < 4; ++k) {
    int j = (t + k*256) * 4;
    float4 w = *(const float4*)(nw + j);
    st4(y + j, make_float4(vals[k*4+0]*scale*w.x, vals[k*4+1]*scale*w.y,
                           vals[k*4+2]*scale*w.z, vals[k*4+3]*scale*w.w));
  }
}

extern "C" void kernel_launch(void* const* d_in, const int* in_sizes, int n_in,
                              void* d_out, int out_size, void* d_ws, size_t ws_size,
                              hipStream_t stream) {
  const float* x       = (const float*)d_in[0];
  const float* Wi      = (const float*)d_in[1];
  const float* cw      = (const float*)d_in[2];
  const float* cb      = (const float*)d_in[3];
  const float* dt_bias = (const float*)d_in[4];
  const float* A_log   = (const float*)d_in[5];
  const float* Dp      = (const float*)d_in[6];
  const float* nw      = (const float*)d_in[7];
  const float* Wo      = (const float*)d_in[8];
  float* out = (float*)d_out;

  // ---- workspace layout: identical 143,130,624-byte footprint as R2 -------
  ushort* projb = (ushort*)d_ws;
  ushort* R     = projb + (size_t)ROWS*PROJD;
  ushort* xb    = R;
  ushort* Wib   = R + (size_t)ROWS*EMB;
  ushort* Wob   = R;
  ushort* convb = R;
  float*  dtb   = (float*)(convb + (size_t)ROWS*CONVD);
  float*  acum  = dtb  + (size_t)ROWS*NHEADS;
  float*  Gb    = acum + (size_t)NBATCH*NCH*NHEADS*CHUNK;
  ushort* st    = (ushort*)(Gb + (size_t)NBATCH*NCH*CHUNK*CHUNK);

  size_t need = (size_t)ROWS*PROJD*2 + (size_t)ROWS*CONVD*2
              + (size_t)ROWS*NHEADS*4 + (size_t)NBATCH*NCH*NHEADS*CHUNK*4
              + (size_t)NBATCH*NCH*CHUNK*CHUNK*4
              + (size_t)NBATCH*NCH*NHEADS*HEAD_DIM*STATE*2;
  if (ws_size < need) return;

  // 0. convert x, Wi to bf16
  f32_to_bf16_kernel<<<(int)((long)ROWS*EMB/8/256), 256, 0, stream>>>(x, xb, (long)ROWS*EMB);
  f32_to_bf16_kernel<<<(int)((long)PROJD*EMB/8/256), 256, 0, stream>>>(Wi, Wib, (long)PROJD*EMB);
  // 1. proj = x @ Wi^T  (pipelined MFMA, M=4096, N=8512, K=2048) -> bf16
  //    grid: N-tiles=ceil(8512/256)=34, M-tiles=4096/128=32 -> 1088 blocks (%8==0)
  gemm_pipe_bt<ushort><<<dim3(34, 32), 512, 0, stream>>>(
      xb, EMB, Wib, EMB, projb, PROJD, PROJD, EMB);
  // 2. causal depthwise conv + silu -> bf16 (overwrites xb/Wib: dead)
  conv_silu_kernel<<<(int)(((long)ROWS*(CONVD/4)+255)/256), 256, 0, stream>>>(
      projb, cw, cb, convb);
  // 3. dt = softplus(...)
  dt_kernel<<<ROWS*NHEADS/256, 256, 0, stream>>>(projb, dt_bias, dtb);
  // 4. chunk cumsums of A*dt
  acum_kernel<<<(NBATCH*NCH*NHEADS+255)/256, 256, 0, stream>>>(dtb, A_log, acum);
  // 5. G[l,s] = sum_n C[l,n]*B[s,n] per (b,chunk)
  gemm_bnt<ushort,ushort,float><<<dim3(1,1,NBATCH*NCH), 256, 0, stream>>>(
      convb + INTER + STATE, CONVD, (long)CHUNK*CONVD,
      convb + INTER,         CONVD, (long)CHUNK*CONVD,
      Gb, CHUNK, (long)CHUNK*CHUNK, CHUNK, CHUNK, CHUNK);
  // 6. per-chunk end states -> bf16 (MFMA)
  states_mfma_kernel<<<dim3(NHEADS, NCH, NBATCH), 256, 0, stream>>>(convb, dtb, acum, st);
  // 7. sequential inter-chunk scan (in place)
  scan_kernel<<<NBATCH*NHEADS, 256, 0, stream>>>(st, acum);
  // 8. y = Y_diag + Y_off + D*hid  (MFMA; into proj cols [INTER, 2*INTER))
  y_mfma_kernel<<<dim3(NHEADS, NCH*2, NBATCH), 256, 0, stream>>>(
      convb, dtb, acum, Gb, st, Dp, projb);
  // 9. gating + RMSNorm (in place, bf16)
  gate_norm_kernel<<<ROWS, 256, 0, stream>>>(projb, nw);
  // 9.5 convert Wo to bf16 (overlays dead convb — after y)
  f32_to_bf16_kernel<<<(int)((long)EMB*INTER/8/256), 256, 0, stream>>>(Wo, Wob, (long)EMB*INTER);
  // 10. out = yn @ Wo^T  (pipelined MFMA, M=4096, N=2048, K=4096) -> f32
  //     grid: 8 x 32 = 256 blocks (%8==0, exactly 1 per CU)
  gemm_pipe_bt<float><<<dim3(8, 32), 512, 0, stream>>>(
      projb + INTER, PROJD, Wob, INTER, out, EMB, EMB, INTER);
}

// Round 8
// 618.985 us; speedup vs baseline: 1.1907x; 1.1907x over previous
//
#include <hip/hip_runtime.h>
#include <math.h>

#define NHEADS   64
#define EMB      2048
#define STATE    128
#define KCONV    4
#define HEAD_DIM 64
#define CHUNK    128
#define SEQL     2048
#define NBATCH   2
#define NCH      (SEQL/CHUNK)          // 16
#define INTER    (NHEADS*HEAD_DIM)     // 4096
#define CONVD    (INTER + 2*STATE)     // 4352
#define PROJD    (INTER + CONVD + NHEADS) // 8512
#define ROWS     (NBATCH*SEQL)         // 4096
#define EPSV     1e-6f

__device__ __forceinline__ float sigmoidf_(float x){ return 1.f/(1.f+__expf(-x)); }

// ---- bf16 (stored as ushort) helpers, f32 math everywhere -----------------
__device__ __forceinline__ float b2f(ushort u){
  union{float f; unsigned u;} x; x.u = ((unsigned)u)<<16; return x.f;
}
__device__ __forceinline__ ushort f2b(float f){
  union{float f; unsigned u;} x; x.f=f;
  unsigned r = x.u + 0x7FFFu + ((x.u>>16)&1u);
  return (ushort)(r>>16);
}
__device__ __forceinline__ float4 ld4(const float* p){ return *(const float4*)p; }
__device__ __forceinline__ float4 ld4(const ushort* p){
  ushort4 v = *(const ushort4*)p;
  return make_float4(b2f(v.x),b2f(v.y),b2f(v.z),b2f(v.w));
}
__device__ __forceinline__ void st4(float* p, float4 v){ *(float4*)p = v; }
__device__ __forceinline__ void st4(ushort* p, float4 v){
  ushort4 o; o.x=f2b(v.x); o.y=f2b(v.y); o.z=f2b(v.z); o.w=f2b(v.w);
  *(ushort4*)p = o;
}
__device__ __forceinline__ void stc(float* p, float v){ *p = v; }
__device__ __forceinline__ void stc(ushort* p, float v){ *p = f2b(v); }

// ---------------------------------------------------------------------------
// f32 -> bf16 bulk convert (n multiple of 8)
// ---------------------------------------------------------------------------
__global__ __launch_bounds__(256) void f32_to_bf16_kernel(
    const float* __restrict__ in, ushort* __restrict__ out, long n)
{
  long i = ((long)blockIdx.x*256 + threadIdx.x) * 8;
  if (i >= n) return;
  float4 a = *(const float4*)(in + i);
  float4 b = *(const float4*)(in + i + 4);
  st4(out + i, a);
  st4(out + i + 4, b);
}

typedef __attribute__((ext_vector_type(8))) short short8v;   // 8 bf16 = 4 VGPR
typedef __attribute__((ext_vector_type(4))) float float4v;

#define GLL16(g, l) __builtin_amdgcn_global_load_lds( \
    (const __attribute__((address_space(1))) void*)(g), \
    (__attribute__((address_space(3))) void*)(l), 16, 0, 0)

// ---------------------------------------------------------------------------
// MFMA bf16 NT GEMM (m97 structure, R6-verified) + conflict-free LDS swizzle
// (R7-verified: source-col XOR + read XOR, SQ_LDS_BANK_CONFLICT -> 0).
// 128x128 tile, BK=32, 256 threads = 4 waves. XCD-aware tile swizzle.
// ---------------------------------------------------------------------------
template<typename TC>
__global__ __launch_bounds__(256) void gemm_mfma_bt(
    const ushort* __restrict__ A, int lda,
    const ushort* __restrict__ B, int ldb,
    TC* __restrict__ C, int ldc,
    int N, int K)
{
  __shared__ ushort As[128*32];
  __shared__ ushort Bs[128*32];
  const int t = threadIdx.x;
  const int lt = t & 63, w = t >> 6;
  const int wr = w >> 1, wc = w & 1;

  // XCD-aware bijective swizzle (both call sites have nwg % 8 == 0)
  const int nwg = gridDim.x * gridDim.y;
  int orig = blockIdx.x + gridDim.x * blockIdx.y;
  int tile = orig;
  if ((nwg & 7) == 0) tile = (orig & 7) * (nwg >> 3) + (orig >> 3);
  const int m0 = (tile / gridDim.x) * 128;
  const int n0 = (tile % gridDim.x) * 128;

  float4v acc[4][4];
  #pragma unroll
  for (int i=0;i<4;++i)
    #pragma unroll
    for (int j=0;j<4;++j) acc[i][j] = float4v{0.f,0.f,0.f,0.f};

  const int srow = t >> 2;            // LDS row 0..63 (and +64 for 2nd GLL)
  // swizzled SOURCE col so linear LDS dest + swizzled read match (rule #21)
  const int scol = ((t & 3) ^ ((srow >> 1) & 3)) * 8;
  const int bn0 = min(n0 + srow, N-1);
  const int bn1 = min(n0 + 64 + srow, N-1);
  const long aoff0 = (long)(m0 + srow) * lda + scol;
  const long aoff1 = (long)(m0 + 64 + srow) * lda + scol;
  const long boff0 = (long)bn0 * ldb + scol;
  const long boff1 = (long)bn1 * ldb + scol;
  const int lr = lt & 15, lks = lt >> 4;

  for (int k0 = 0; k0 < K; k0 += 32) {
    GLL16(A + aoff0 + k0, As + t*8);
    GLL16(A + aoff1 + k0, As + 2048 + t*8);
    GLL16(B + boff0 + k0, Bs + t*8);
    GLL16(B + boff1 + k0, Bs + 2048 + t*8);
    __syncthreads();
    short8v af[4], bf[4];
    #pragma unroll
    for (int i = 0; i < 4; ++i) {
      int ra = wr*64 + i*16 + lr;
      af[i] = *(const short8v*)(As + ra*32 + ((lks ^ ((ra>>1)&3)) << 3));
      int rb = wc*64 + i*16 + lr;
      bf[i] = *(const short8v*)(Bs + rb*32 + ((lks ^ ((rb>>1)&3)) << 3));
    }
    #pragma unroll
    for (int i = 0; i < 4; ++i)
      #pragma unroll
      for (int j = 0; j < 4; ++j)
        acc[i][j] = __builtin_amdgcn_mfma_f32_16x16x32_bf16(af[i], bf[j], acc[i][j], 0, 0, 0);
    __syncthreads();
  }

  const int cr = (lt >> 4) * 4;   // C/D: col=lane&15, row=(lane>>4)*4+reg (m89)
  const int cc = lt & 15;
  #pragma unroll
  for (int i = 0; i < 4; ++i) {
    #pragma unroll
    for (int j = 0; j < 4; ++j) {
      int col = n0 + wc*64 + j*16 + cc;
      if (col < N) {
        #pragma unroll
        for (int r = 0; r < 4; ++r) {
          int row = m0 + wr*64 + i*16 + cr + r;
          stc(C + (long)row*ldc + col, acc[i][j][r]);
        }
      }
    }
  }
}

// ---------------------------------------------------------------------------
// MFMA G kernel: G[l,s] = sum_n C[l,n]*B[s,n] per (b,c). Exact bf16 operands,
// both k-contiguous rows of convb (no transpose staging). 4 waves; wave w owns
// l-rows w*32..w*32+31 (2 m-frags), all 8 s-frags; 64 MFMA.
// ---------------------------------------------------------------------------
__global__ __launch_bounds__(256) void g_mfma_kernel(
    const ushort* __restrict__ conv, float* __restrict__ G)
{
  const int bc = blockIdx.x;
  const long r0 = (long)bc*CHUNK;
  __shared__ ushort Cs[128][136];   // C rows [l][n]
  __shared__ ushort Bs[128][136];   // B rows [s][n]
  const int t = threadIdx.x;
  const int lt = t & 63, w = t >> 6;
  const int lr = lt & 15, lk = (lt >> 4) * 8;

  for (int i = t; i < 128*16; i += 256) {
    int r = i >> 4, n0 = (i & 15) * 8;
    *(short8v*)&Cs[r][n0] = *(const short8v*)(conv + (r0+r)*CONVD + INTER + STATE + n0);
    *(short8v*)&Bs[r][n0] = *(const short8v*)(conv + (r0+r)*CONVD + INTER + n0);
  }
  __syncthreads();

  float4v acc[2][8];
  #pragma unroll
  for (int m=0;m<2;++m)
    #pragma unroll
    for (int j=0;j<8;++j) acc[m][j] = float4v{0,0,0,0};
  #pragma unroll
  for (int kk = 0; kk < 4; ++kk) {
    short8v a0 = *(const short8v*)&Cs[w*32 +      lr][kk*32 + lk];
    short8v a1 = *(const short8v*)&Cs[w*32 + 16 + lr][kk*32 + lk];
    #pragma unroll
    for (int nj = 0; nj < 8; ++nj) {
      short8v bv = *(const short8v*)&Bs[nj*16 + lr][kk*32 + lk];
      acc[0][nj] = __builtin_amdgcn_mfma_f32_16x16x32_bf16(a0, bv, acc[0][nj], 0, 0, 0);
      acc[1][nj] = __builtin_amdgcn_mfma_f32_16x16x32_bf16(a1, bv, acc[1][nj], 0, 0, 0);
    }
  }
  float* Gb = G + (long)bc*CHUNK*CHUNK;
  const int cr = (lt >> 4) * 4, cc = lt & 15;
  #pragma unroll
  for (int m = 0; m < 2; ++m)
    #pragma unroll
    for (int nj = 0; nj < 8; ++nj)
      #pragma unroll
      for (int r = 0; r < 4; ++r)
        Gb[(w*32 + m*16 + cr + r)*CHUNK + nj*16 + cc] = acc[m][nj][r];
}

// ---------------------------------------------------------------------------
// Depthwise causal conv (K=4) + bias + SiLU over proj cols [INTER, INTER+CONVD)
// ---------------------------------------------------------------------------
__global__ __launch_bounds__(256) void conv_silu_kernel(
    const ushort* __restrict__ proj, const float* __restrict__ cw,
    const float* __restrict__ cb, ushort* __restrict__ out)
{
  const int C4 = CONVD/4;
  long idx = (long)blockIdx.x*256 + threadIdx.x;
  if (idx >= (long)ROWS*C4) return;
  int r = (int)(idx / C4);
  int c = (int)(idx % C4) * 4;
  int tt = r & (SEQL-1);
  float4 bv = *(const float4*)(cb + c);
  float acc0=bv.x, acc1=bv.y, acc2=bv.z, acc3=bv.w;
  float4 w0 = *(const float4*)(cw + (c+0)*KCONV);
  float4 w1 = *(const float4*)(cw + (c+1)*KCONV);
  float4 w2 = *(const float4*)(cw + (c+2)*KCONV);
  float4 w3 = *(const float4*)(cw + (c+3)*KCONV);
  const float wj0[4] = {w0.x,w0.y,w0.z,w0.w};
  const float wj1[4] = {w1.x,w1.y,w1.z,w1.w};
  const float wj2[4] = {w2.x,w2.y,w2.z,w2.w};
  const float wj3[4] = {w3.x,w3.y,w3.z,w3.w};
  #pragma unroll
  for (int j = 0; j < KCONV; ++j) {
    int tr = tt - (KCONV-1) + j;
    if (tr >= 0) {
      float4 v = ld4(proj + (long)(r - (KCONV-1) + j)*PROJD + INTER + c);
      acc0 = fmaf(v.x, wj0[j], acc0);
      acc1 = fmaf(v.y, wj1[j], acc1);
      acc2 = fmaf(v.z, wj2[j], acc2);
      acc3 = fmaf(v.w, wj3[j], acc3);
    }
  }
  float4 o;
  o.x = acc0 * sigmoidf_(acc0);
  o.y = acc1 * sigmoidf_(acc1);
  o.z = acc2 * sigmoidf_(acc2);
  o.w = acc3 * sigmoidf_(acc3);
  st4(out + (long)r*CONVD + c, o);
}

// ---------------------------------------------------------------------------
// Fused dt (softplus) + per-chunk cumsum of A*dt. One block per (b,chunk).
// ---------------------------------------------------------------------------
__global__ __launch_bounds__(256) void dt_acum_kernel(
    const ushort* __restrict__ proj, const float* __restrict__ dt_bias,
    const float* __restrict__ A_log, float* __restrict__ dtb,
    float* __restrict__ acum)
{
  const int bc = blockIdx.x;           // 32 blocks
  const long r0 = (long)bc*CHUNK;
  __shared__ float dts[CHUNK][NHEADS+1];
  const int t = threadIdx.x;
  for (int i = t; i < CHUNK*8; i += 256) {
    int l = i >> 3, h0 = (i & 7) * 8;
    short8v v = *(const short8v*)(proj + (r0+l)*PROJD + INTER + CONVD + h0);
    #pragma unroll
    for (int j = 0; j < 8; ++j) {
      float xv = b2f((ushort)v[j]) + dt_bias[h0+j];
      float sp = fmaxf(xv, 0.f) + __logf(1.f + __expf(-fabsf(xv)));
      dts[l][h0+j] = sp;
      dtb[(r0+l)*NHEADS + h0 + j] = sp;
    }
  }
  __syncthreads();
  if (t < NHEADS) {
    float Ah = -__expf(A_log[t]);
    float acc = 0.f;
    float* o = acum + ((long)bc*NHEADS + t)*CHUNK;
    for (int l = 0; l < CHUNK; ++l) { acc = fmaf(Ah, dts[l][t], acc); o[l] = acc; }
  }
}

// ---------------------------------------------------------------------------
// MFMA states kernel: states[p,n] = sum_l (w[l]*hid[l,p]) * B[l,n]
// ---------------------------------------------------------------------------
__global__ __launch_bounds__(256) void states_mfma_kernel(
    const ushort* __restrict__ conv, const float* __restrict__ dtb,
    const float* __restrict__ acum, ushort* __restrict__ states)
{
  const int h = blockIdx.x, c = blockIdx.y, b = blockIdx.z;
  const int bc = b*NCH + c;
  const long r0 = (long)bc*CHUNK;
  __shared__ ushort Ahi[64][136];   // (w*hid)^T hi: [p][l]
  __shared__ ushort Alo[64][136];   // lo residual
  __shared__ ushort Bt[128][136];   // B^T: [n][l]
  __shared__ float arow[CHUNK];
  __shared__ float wrow[CHUNK];
  const int t = threadIdx.x;
  const int lt = t & 63, w = t >> 6;
  const int lr = lt & 15, lk = (lt >> 4) * 8;

  if (t < CHUNK) arow[t] = acum[((long)bc*NHEADS + h)*CHUNK + t];
  __syncthreads();
  if (t < CHUNK) wrow[t] = dtb[(r0 + t)*NHEADS + h] * __expf(arow[CHUNK-1] - arow[t]);
  __syncthreads();

  for (int i = t; i < CHUNK*HEAD_DIM/8; i += 256) {
    int l = i >> 3, p0 = (i & 7) * 8;
    short8v v = *(const short8v*)(conv + (r0+l)*CONVD + h*HEAD_DIM + p0);
    float wl = wrow[l];
    #pragma unroll
    for (int j = 0; j < 8; ++j) {
      float f = b2f((ushort)v[j]) * wl;
      ushort hb = f2b(f);
      Ahi[p0+j][l] = hb;
      Alo[p0+j][l] = f2b(f - b2f(hb));
    }
  }
  for (int i = t; i < CHUNK*STATE/8; i += 256) {
    int l = i >> 4, n0 = (i & 15) * 8;
    short8v v = *(const short8v*)(conv + (r0+l)*CONVD + INTER + n0);
    #pragma unroll
    for (int j = 0; j < 8; ++j) Bt[n0+j][l] = (ushort)v[j];
  }
  __syncthreads();

  float4v acc[8];
  #pragma unroll
  for (int j = 0; j < 8; ++j) acc[j] = float4v{0,0,0,0};
  #pragma unroll
  for (int kk = 0; kk < 4; ++kk) {
    short8v ahi = *(const short8v*)&Ahi[w*16 + lr][kk*32 + lk];
    short8v alo = *(const short8v*)&Alo[w*16 + lr][kk*32 + lk];
    #pragma unroll
    for (int nj = 0; nj < 8; ++nj) {
      short8v bv = *(const short8v*)&Bt[nj*16 + lr][kk*32 + lk];
      acc[nj] = __builtin_amdgcn_mfma_f32_16x16x32_bf16(ahi, bv, acc[nj], 0, 0, 0);
      acc[nj] = __builtin_amdgcn_mfma_f32_16x16x32_bf16(alo, bv, acc[nj], 0, 0, 0);
    }
  }
  ushort* so = states + ((long)bc*NHEADS + h)*HEAD_DIM*STATE;
  const int cr = (lt >> 4) * 4, cc = lt & 15;
  #pragma unroll
  for (int nj = 0; nj < 8; ++nj)
    #pragma unroll
    for (int r = 0; r < 4; ++r)
      so[(w*16 + cr + r)*STATE + nj*16 + cc] = f2b(acc[nj][r]);
}

// in-place inter-chunk scan: states[c] <- init_state entering chunk c
// 512 blocks: (b*NHEADS+h)*4 + p-quarter
__global__ __launch_bounds__(256) void scan_kernel(
    ushort* __restrict__ states, const float* __restrict__ acum)
{
  const int blk = blockIdx.x;
  const int bh = blk >> 2, pq = blk & 3;
  const int b = bh >> 6, h = bh & 63;
  const int t = threadIdx.x;
  const int base = pq * 16 * STATE;   // 16 p-rows per quarter
  float acc[8];
  #pragma unroll
  for (int i=0;i<8;++i) acc[i]=0.f;
  for (int c = 0; c < NCH; ++c) {
    const long bch = ((long)(b*NCH + c)*NHEADS + h);
    float lam = __expf(acum[bch*CHUNK + CHUNK-1]);
    ushort* sb = states + bch*HEAD_DIM*STATE + base;
    #pragma unroll
    for (int i = 0; i < 8; ++i) {
      float v = b2f(sb[t + i*256]);
      sb[t + i*256] = f2b(acc[i]);
      acc[i] = fmaf(acc[i], lam, v);
    }
  }
}

// ---------------------------------------------------------------------------
// MFMA y-kernel (verified R5/R6)
// ---------------------------------------------------------------------------
__global__ __launch_bounds__(256) void y_mfma_kernel(
    const ushort* __restrict__ conv, const float* __restrict__ dtb,
    const float* __restrict__ acum, const float* __restrict__ G,
    const ushort* __restrict__ states, const float* __restrict__ Dp,
    ushort* __restrict__ proj)
{
  const int h = blockIdx.x;
  const int c = blockIdx.y >> 1, mh = blockIdx.y & 1;
  const int b = blockIdx.z;
  const int bc = b*NCH + c;
  const int mbase = mh * 64;
  const long r0 = (long)bc*CHUNK;

  __shared__ float  Af[64][132];     // W (f32), then C (f32 from bf16, exact)
  __shared__ ushort B0[64][136];     // hid^T: B0[p][s], s over FULL chunk
  __shared__ ushort B1[64][136];     // init:  B1[p][n]
  __shared__ float arow[CHUNK];
  __shared__ float dtr[CHUNK];
  __shared__ float el[64];

  const int t = threadIdx.x;
  const int lt = t & 63, w = t >> 6;
  const int lr = lt & 15, lk = (lt >> 4) * 8;

  if (t < CHUNK) {
    arow[t] = acum[((long)bc*NHEADS + h)*CHUNK + t];
    dtr[t]  = dtb[(r0 + t)*NHEADS + h];
  }
  __syncthreads();

  if (t < 64) el[t] = __expf(arow[mbase + t]);
  for (int i = t; i < CHUNK*HEAD_DIM/8; i += 256) {
    int s = i >> 3, p0 = (i & 7) * 8;
    short8v v = *(const short8v*)(conv + (r0+s)*CONVD + h*HEAD_DIM + p0);
    #pragma unroll
    for (int j = 0; j < 8; ++j) B0[p0+j][s] = (ushort)v[j];
  }
  {
    const ushort* stb = states + ((long)bc*NHEADS + h)*HEAD_DIM*STATE;
    for (int i = t; i < HEAD_DIM*STATE/8; i += 256) {
      int p = i >> 4, n0 = (i & 15) * 8;
      *(short8v*)&B1[p][n0] = *(const short8v*)(stb + p*STATE + n0);
    }
  }
  {
    const float* Gb = G + (long)bc*CHUNK*CHUNK;
    for (int i = t; i < 64*CHUNK; i += 256) {
      int ll = i >> 7, s = i & 127;
      int l = mbase + ll;
      float wv = 0.f;
      if (s <= l) wv = Gb[l*CHUNK + s] * __expf(arow[l] - arow[s]) * dtr[s];
      Af[ll][s] = wv;
    }
  }
  __syncthreads();

  float4v acc1[4], acc2[4];
  #pragma unroll
  for (int j = 0; j < 4; ++j) { acc1[j] = float4v{0,0,0,0}; acc2[j] = float4v{0,0,0,0}; }

  // mm1: Y_diag, W split hi/lo
  #pragma unroll
  for (int kk = 0; kk < 4; ++kk) {
    const float* ap = &Af[w*16 + lr][kk*32 + lk];
    float a8[8];
    *(float4*)&a8[0] = *(const float4*)ap;
    *(float4*)&a8[4] = *(const float4*)(ap + 4);
    short8v ahi, alo;
    #pragma unroll
    for (int e = 0; e < 8; ++e) {
      ushort hb = f2b(a8[e]);
      float rem = a8[e] - b2f(hb);
      ahi[e] = (short)hb;
      alo[e] = (short)f2b(rem);
    }
    #pragma unroll
    for (int nj = 0; nj < 4; ++nj) {
      short8v bfv = *(const short8v*)&B0[nj*16 + lr][kk*32 + lk];
      acc1[nj] = __builtin_amdgcn_mfma_f32_16x16x32_bf16(ahi, bfv, acc1[nj], 0, 0, 0);
      acc1[nj] = __builtin_amdgcn_mfma_f32_16x16x32_bf16(alo, bfv, acc1[nj], 0, 0, 0);
    }
  }
  __syncthreads();

  for (int i = t; i < 64*STATE; i += 256) {
    int ll = i >> 7, n = i & 127;
    Af[ll][n] = b2f(conv[(r0 + mbase + ll)*CONVD + INTER + STATE + n]);
  }
  __syncthreads();

  // mm2: C @ init^T (exact)
  #pragma unroll
  for (int kk = 0; kk < 4; ++kk) {
    const float* ap = &Af[w*16 + lr][kk*32 + lk];
    float a8[8];
    *(float4*)&a8[0] = *(const float4*)ap;
    *(float4*)&a8[4] = *(const float4*)(ap + 4);
    short8v ahi;
    #pragma unroll
    for (int e = 0; e < 8; ++e) ahi[e] = (short)f2b(a8[e]);
    #pragma unroll
    for (int nj = 0; nj < 4; ++nj) {
      short8v bfv = *(const short8v*)&B1[nj*16 + lr][kk*32 + lk];
      acc2[nj] = __builtin_amdgcn_mfma_f32_16x16x32_bf16(ahi, bfv, acc2[nj], 0, 0, 0);
    }
  }

  const float Dh = Dp[h];
  const int cr = (lt >> 4) * 4, cc = lt & 15;
  #pragma unroll
  for (int nj = 0; nj < 4; ++nj) {
    int p = nj*16 + cc;
    #pragma unroll
    for (int r = 0; r < 4; ++r) {
      int ll = w*16 + cr + r;
      float hid_raw = b2f(B0[p][mbase + ll]);
      float yv = acc1[nj][r] + el[ll]*acc2[nj][r] + Dh*hid_raw;
      proj[(r0 + mbase + ll)*PROJD + INTER + h*HEAD_DIM + p] = f2b(yv);
    }
  }
}

// yg = y*silu(gate); rmsnorm; write yn back in place (per row)
__global__ __launch_bounds__(256) void gate_norm_kernel(
    ushort* __restrict__ proj, const float* __restrict__ nw)
{
  const int r = blockIdx.x;
  const int t = threadIdx.x;
  __shared__ float red[256];
  ushort* gate = proj + (long)r*PROJD;
  ushort* y = gate + INTER;
  float vals[16];
  float ss = 0.f;
  #pragma unroll
  for (int k = 0; k < 4; ++k) {
    int j = (t + k*256) * 4;
    float4 g = ld4(gate + j);
    float4 yv = ld4(y + j);
    float v0 = yv.x * g.x * sigmoidf_(g.x);
    float v1 = yv.y * g.y * sigmoidf_(g.y);
    float v2 = yv.z * g.z * sigmoidf_(g.z);
    float v3 = yv.w * g.w * sigmoidf_(g.w);
    vals[k*4+0]=v0; vals[k*4+1]=v1; vals[k*4+2]=v2; vals[k*4+3]=v3;
    ss += v0*v0 + v1*v1 + v2*v2 + v3*v3;
  }
  red[t] = ss;
  __syncthreads();
  for (int sft = 128; sft > 0; sft >>= 1) {
    if (t < sft) red[t] += red[t+sft];
    __syncthreads();
  }
  float scale = rsqrtf(red[0] / (float)INTER + EPSV);
  #pragma unroll
  for (int k = 0; k < 4; ++k) {
    int j = (t + k*256) * 4;
    float4 w = *(const float4*)(nw + j);
    st4(y + j, make_float4(vals[k*4+0]*scale*w.x, vals[k*4+1]*scale*w.y,
                           vals[k*4+2]*scale*w.z, vals[k*4+3]*scale*w.w));
  }
}

extern "C" void kernel_launch(void* const* d_in, const int* in_sizes, int n_in,
                              void* d_out, int out_size, void* d_ws, size_t ws_size,
                              hipStream_t stream) {
  const float* x       = (const float*)d_in[0];
  const float* Wi      = (const float*)d_in[1];
  const float* cw      = (const float*)d_in[2];
  const float* cb      = (const float*)d_in[3];
  const float* dt_bias = (const float*)d_in[4];
  const float* A_log   = (const float*)d_in[5];
  const float* Dp      = (const float*)d_in[6];
  const float* nw      = (const float*)d_in[7];
  const float* Wo      = (const float*)d_in[8];
  float* out = (float*)d_out;

  // ---- workspace layout: identical 143,130,624-byte footprint as R2 -------
  ushort* projb = (ushort*)d_ws;
  ushort* R     = projb + (size_t)ROWS*PROJD;
  ushort* xb    = R;
  ushort* Wib   = R + (size_t)ROWS*EMB;
  ushort* Wob   = R;
  ushort* convb = R;
  float*  dtb   = (float*)(convb + (size_t)ROWS*CONVD);
  float*  acum  = dtb  + (size_t)ROWS*NHEADS;
  float*  Gb    = acum + (size_t)NBATCH*NCH*NHEADS*CHUNK;
  ushort* st    = (ushort*)(Gb + (size_t)NBATCH*NCH*CHUNK*CHUNK);

  size_t need = (size_t)ROWS*PROJD*2 + (size_t)ROWS*CONVD*2
              + (size_t)ROWS*NHEADS*4 + (size_t)NBATCH*NCH*NHEADS*CHUNK*4
              + (size_t)NBATCH*NCH*CHUNK*CHUNK*4
              + (size_t)NBATCH*NCH*NHEADS*HEAD_DIM*STATE*2;
  if (ws_size < need) return;

  // 0. convert x, Wi to bf16
  f32_to_bf16_kernel<<<(int)((long)ROWS*EMB/8/256), 256, 0, stream>>>(x, xb, (long)ROWS*EMB);
  f32_to_bf16_kernel<<<(int)((long)PROJD*EMB/8/256), 256, 0, stream>>>(Wi, Wib, (long)PROJD*EMB);
  // 1. proj = x @ Wi^T  (MFMA, M=4096, N=8512, K=2048) -> bf16; grid 67x32=2144
  gemm_mfma_bt<ushort><<<dim3((PROJD+127)/128, ROWS/128), 256, 0, stream>>>(
      xb, EMB, Wib, EMB, projb, PROJD, PROJD, EMB);
  // 2. causal depthwise conv + silu -> bf16 (overwrites xb/Wib: dead)
  conv_silu_kernel<<<(int)(((long)ROWS*(CONVD/4)+255)/256), 256, 0, stream>>>(
      projb, cw, cb, convb);
  // 3. fused dt softplus + chunk cumsum of A*dt
  dt_acum_kernel<<<NBATCH*NCH, 256, 0, stream>>>(projb, dt_bias, A_log, dtb, acum);
  // 4. G[l,s] = sum_n C[l,n]*B[s,n] per (b,chunk)  (MFMA)
  g_mfma_kernel<<<NBATCH*NCH, 256, 0, stream>>>(convb, Gb);
  // 5. per-chunk end states -> bf16 (MFMA)
  states_mfma_kernel<<<dim3(NHEADS, NCH, NBATCH), 256, 0, stream>>>(convb, dtb, acum, st);
  // 6. sequential inter-chunk scan (in place, 4-way p-split)
  scan_kernel<<<NBATCH*NHEADS*4, 256, 0, stream>>>(st, acum);
  // 7. y = Y_diag + Y_off + D*hid  (MFMA; into proj cols [INTER, 2*INTER))
  y_mfma_kernel<<<dim3(NHEADS, NCH*2, NBATCH), 256, 0, stream>>>(
      convb, dtb, acum, Gb, st, Dp, projb);
  // 8. gating + RMSNorm (in place, bf16)
  gate_norm_kernel<<<ROWS, 256, 0, stream>>>(projb, nw);
  // 8.5 convert Wo to bf16 (overlays dead convb — after y)
  f32_to_bf16_kernel<<<(int)((long)EMB*INTER/8/256), 256, 0, stream>>>(Wo, Wob, (long)EMB*INTER);
  // 9. out = yn @ Wo^T  (MFMA, M=4096, N=2048, K=4096) -> f32; grid 16x32=512
  gemm_mfma_bt<float><<<dim3(EMB/128, ROWS/128), 256, 0, stream>>>(
      projb + INTER, PROJD, Wob, INTER, out, EMB, EMB, INTER);
}